// Round 1
// baseline (136.372 us; speedup 1.0000x reference)
//
#include <hip/hip_runtime.h>

// Problem constants (fixed by the reference).
#define N_NODES 10000
#define DEG     32
#define CH      16
#define IN_DIM  4
#define BATCH   8
#define E_EDGES (N_NODES * DEG)        // 320000
#define WI_STRIDE (E_EDGES * CH)       // 5,120,000 floats between w[i] planes
#define P_COUNT 625                    // 512*625 == E_EDGES : gather period in n
#define LX_STRIDE 36                   // 32 floats/row + 4 pad (16B-aligned)

// Single fused kernel: one block per p (0..624), 1024 threads = 16 waves.
// Gather index k = (512n+16d+c) mod 320000 = 512p + 16d + c for every
// n = p + 625*j, so all 16 waves (one n each) share the same 512 gathered
// node rows -> stage them once in LDS, read exactly once per wave (no
// redundancy; 1 MB LDS reads/block).
//
// Change vs r0 (two-kernel version):
//  - transpose kernel eliminated: Stage A reads x[b][node][0..3] (16 B)
//    directly. x is 1.28 MB -> fully L2-resident on every XCD, so losing
//    the 128 B-coalesced layout costs only overlapped L2 bandwidth while
//    saving a launch, a serializing dependency, and 2.56 MB of HBM.
//    nd == N_NODES (the zero-pad row) is handled with a predicated load.
//  - Stage B weight loads software-pipelined: prefetch ds+1's 4 chunks
//    (256 B contiguous per wave-instruction) during ds's FMAs, and issue
//    the ds=0 chunk before __syncthreads so it flies under the gather.
//    Keeps ~2 KB/wave in flight instead of ~1 KB at 75% duty.
__global__ __launch_bounds__(1024, 8) void lcg_main(
    const float* __restrict__ x,      // [8][10000][4]
    const int*   __restrict__ edges,  // [E] (int32 on device)
    const float* __restrict__ w,      // [4][E][16]
    float*       __restrict__ out)    // [8][N][16]
{
    __shared__ float lx[512 * LX_STRIDE];   // 73728 B -> 2 blocks/CU, 32 waves/CU

    int p = blockIdx.x;
    int t = threadIdx.x;

    int lane = t & 63;
    int j    = t >> 6;                // wave id = node group
    int c    = lane & 15;
    int dq   = lane >> 4;             // 0..3
    int n    = p + P_COUNT * j;

    // weight base: w[i][32n + (4ds+dq)][c] = w + i*WI_STRIDE + n*512 + 64*ds + lane
    const float* wb = w + n * (DEG * CH) + lane;

    // Prefetch ds=0 weights; the compiler's vmcnt(0)-before-barrier drains
    // them together with the Stage A gathers, so this is free overlap.
    float w0 = wb[0];
    float w1 = wb[WI_STRIDE];
    float w2 = wb[2 * WI_STRIDE];
    float w3 = wb[3 * WI_STRIDE];

    // ---- Stage A: edges + direct gather from x into LDS (rows s = 0..511) ----
    {
        int b  = t & 7;               // batch index = which 16 B chunk of the row
        int rg = t >> 3;              // 0..127 ; rows s = rg + 128k, k<4
        const int* ep = edges + 512 * p;
        int nd[4];
#pragma unroll
        for (int k = 0; k < 4; k++) nd[k] = ep[rg + 128 * k];
#pragma unroll
        for (int k = 0; k < 4; k++) {
            int s = rg + 128 * k;
            float4 v = make_float4(0.f, 0.f, 0.f, 0.f);
            if (nd[k] < N_NODES)      // nd == N_NODES is the implicit zero row
                v = *(const float4*)(x + (b * N_NODES + nd[k]) * 4);
            *(float4*)(&lx[s * LX_STRIDE + b * 4]) = v;
        }
    }
    __syncthreads();

    // ---- Stage B ----
    float acc[BATCH];
#pragma unroll
    for (int b = 0; b < BATCH; b++) acc[b] = 0.0f;

    // LDS row for (d = 4ds+dq, c): s = 16d + c -> base (16dq + c)*36, step 64*36
    const float* lrow = &lx[(16 * dq + c) * LX_STRIDE];

#pragma unroll 1
    for (int ds = 0; ds < 8; ds++) {
        // Prefetch next iteration's weights (ds=7 harmlessly re-reads ds=0's
        // chunk from L1 instead of risking an out-of-bounds tail read).
        int nxt = 64 * ((ds + 1) & 7);
        float nw0 = wb[nxt];
        float nw1 = wb[nxt + WI_STRIDE];
        float nw2 = wb[nxt + 2 * WI_STRIDE];
        float nw3 = wb[nxt + 3 * WI_STRIDE];

        const float* lr = lrow + ds * (64 * LX_STRIDE);
#pragma unroll
        for (int b = 0; b < BATCH; b++) {
            float4 xq = *(const float4*)(lr + 4 * b);
            acc[b] += xq.x * w0 + xq.y * w1 + xq.z * w2 + xq.w * w3;
        }
        w0 = nw0; w1 = nw1; w2 = nw2; w3 = nw3;
    }

    // reduce over dq groups (lanes l, l^16, l^32, l^48)
#pragma unroll
    for (int b = 0; b < BATCH; b++) {
        acc[b] += __shfl_xor(acc[b], 16, 64);
        acc[b] += __shfl_xor(acc[b], 32, 64);
    }

    // dq group g stores batches 2g, 2g+1 (16 c-lanes -> one 64 B line per b)
    int ob = n * CH + c;
    out[(2 * dq + 0) * (N_NODES * CH) + ob] = acc[2 * dq + 0];
    out[(2 * dq + 1) * (N_NODES * CH) + ob] = acc[2 * dq + 1];
}

extern "C" void kernel_launch(void* const* d_in, const int* in_sizes, int n_in,
                              void* d_out, int out_size, void* d_ws, size_t ws_size,
                              hipStream_t stream) {
    const float* x     = (const float*)d_in[0];   // [8][10000][4] f32
    const int*   edges = (const int*)d_in[1];     // [320000] int
    const float* w     = (const float*)d_in[2];   // [4][320000][16] f32
    float* out = (float*)d_out;                   // [8][10000][16] f32
    (void)d_ws; (void)ws_size;                    // workspace no longer used

    lcg_main<<<P_COUNT, 1024, 0, stream>>>(x, edges, w, out);
}

// Round 2
// 131.544 us; speedup vs baseline: 1.0367x; 1.0367x over previous
//
#include <hip/hip_runtime.h>

// Problem constants (fixed by the reference).
#define N_NODES 10000
#define DEG     32
#define CH      16
#define IN_DIM  4
#define BATCH   8
#define E_EDGES (N_NODES * DEG)        // 320000
#define WI_STRIDE (E_EDGES * CH)       // 5,120,000 floats between w[i] planes
#define P_COUNT 625                    // 512*625 == E_EDGES : gather period in n
#define LX_STRIDE 36                   // 32 floats/row + 4 pad (16B-aligned)

// Kernel 1: transpose/pad x[B][N][4] -> xt[N+1][B][4] (node-major, 128 B/node).
// r1 ablation showed this kernel pays for itself: gathering 128 B node rows
// (8 lanes x float4, contiguous) touches 4x fewer L2 lines per Stage-A wave
// than 16 B-granule direct gathers from x (batch chunks 160 KB apart).
__global__ __launch_bounds__(256) void lcg_transpose(const float* __restrict__ x,
                                                     float* __restrict__ xt) {
    int t = blockIdx.x * 256 + threadIdx.x;
    if (t < BATCH * N_NODES) {
        int b = t / N_NODES;
        int node = t - b * N_NODES;
        float4 v = *(const float4*)(x + 4 * t);          // x[b][node][0..3]
        *(float4*)(xt + node * 32 + b * 4) = v;
    } else if (t < BATCH * N_NODES + 8) {
        int r = t - BATCH * N_NODES;                     // zero pad row N_NODES
        *(float4*)(xt + N_NODES * 32 + r * 4) = make_float4(0.f, 0.f, 0.f, 0.f);
    }
}

// Kernel 2: one block per p (0..624), 1024 threads = 16 waves, wave = j
// (n = p + 625*j). Gather index k = (512n+16d+c) mod 320000 = 512p + 16d + c.
// Stage A: gather 512 node-rows (128 B each, contiguous per 8-lane group) into LDS.
// Stage B: lane = c + 16*dq; per iter d = 4*ds + dq. Weight load address for
// plane i is base_i + n*512 + 64*ds + lane -> 64 CONSECUTIVE floats per wave
// instruction (256 B, 4 contiguous lines). Changes vs r0:
//  - depth-2 weight pipeline: ds=0 chunks issued BEFORE __syncthreads (they
//    drain with the gather's vmcnt(0), free overlap); ds+1 prefetched during
//    ds's FMAs -> ~2 KB/wave in flight instead of ~1 KB at 75% duty.
//  - weights loaded non-temporal (read exactly once; don't evict the
//    16x-reused xt rows from L2), out stored non-temporal (write-once).
__global__ __launch_bounds__(1024, 8) void lcg_main(
    const float* __restrict__ xt,     // [N+1][32]
    const int*   __restrict__ edges,  // [E]
    const float* __restrict__ w,      // [4][E][16]
    float*       __restrict__ out)    // [8][N][16]
{
    __shared__ float lx[512 * LX_STRIDE];   // 73728 B -> 2 blocks/CU, 32 waves/CU

    int p = blockIdx.x;
    int t = threadIdx.x;

    int lane = t & 63;
    int j    = t >> 6;                // wave id = node group
    int c    = lane & 15;
    int dq   = lane >> 4;             // 0..3
    int n    = p + P_COUNT * j;

    // weight base: w[i][32n + (4ds+dq)][c] = w + i*WI_STRIDE + n*512 + 64*ds + lane
    const float* wb = w + n * (DEG * CH) + lane;

    // ds=0 prefetch: flies under the Stage-A gather.
    float w0 = __builtin_nontemporal_load(wb);
    float w1 = __builtin_nontemporal_load(wb + WI_STRIDE);
    float w2 = __builtin_nontemporal_load(wb + 2 * WI_STRIDE);
    float w3 = __builtin_nontemporal_load(wb + 3 * WI_STRIDE);

    // ---- Stage A: edges + gather into LDS (rows s = 0..511) ----
    {
        int sub = t & 7;              // which float4 of the 128 B node row
        int rg  = t >> 3;             // 0..127 ; rows s = rg + 128k, k<4
        const int* ep = edges + 512 * p;
        int nd[4];
#pragma unroll
        for (int k = 0; k < 4; k++) nd[k] = ep[rg + 128 * k];
#pragma unroll
        for (int k = 0; k < 4; k++) {
            int s = rg + 128 * k;
            float4 v = *(const float4*)(xt + nd[k] * 32 + sub * 4);
            *(float4*)(&lx[s * LX_STRIDE + sub * 4]) = v;
        }
    }
    __syncthreads();

    // ---- Stage B ----
    float acc[BATCH];
#pragma unroll
    for (int b = 0; b < BATCH; b++) acc[b] = 0.0f;

    // LDS row for (d = 4ds+dq, c): s = 16d + c -> base (16dq + c)*36, step 64*36
    const float* lrow = &lx[(16 * dq + c) * LX_STRIDE];

#pragma unroll 1
    for (int ds = 0; ds < 8; ds++) {
        // Prefetch next iteration's weights (ds=7 harmlessly re-reads ds=0's
        // chunk instead of risking an out-of-bounds tail read).
        int nxt = 64 * ((ds + 1) & 7);
        float nw0 = __builtin_nontemporal_load(wb + nxt);
        float nw1 = __builtin_nontemporal_load(wb + nxt + WI_STRIDE);
        float nw2 = __builtin_nontemporal_load(wb + nxt + 2 * WI_STRIDE);
        float nw3 = __builtin_nontemporal_load(wb + nxt + 3 * WI_STRIDE);

        const float* lr = lrow + ds * (64 * LX_STRIDE);
#pragma unroll
        for (int b = 0; b < BATCH; b++) {
            float4 xq = *(const float4*)(lr + 4 * b);
            acc[b] += xq.x * w0 + xq.y * w1 + xq.z * w2 + xq.w * w3;
        }
        w0 = nw0; w1 = nw1; w2 = nw2; w3 = nw3;
    }

    // reduce over dq groups (lanes l, l^16, l^32, l^48)
#pragma unroll
    for (int b = 0; b < BATCH; b++) {
        acc[b] += __shfl_xor(acc[b], 16, 64);
        acc[b] += __shfl_xor(acc[b], 32, 64);
    }

    // dq group g stores batches 2g, 2g+1 (16 c-lanes -> one 64 B line per b)
    int ob = n * CH + c;
    __builtin_nontemporal_store(acc[2 * dq + 0],
        out + (2 * dq + 0) * (N_NODES * CH) + ob);
    __builtin_nontemporal_store(acc[2 * dq + 1],
        out + (2 * dq + 1) * (N_NODES * CH) + ob);
}

extern "C" void kernel_launch(void* const* d_in, const int* in_sizes, int n_in,
                              void* d_out, int out_size, void* d_ws, size_t ws_size,
                              hipStream_t stream) {
    const float* x     = (const float*)d_in[0];   // [8][10000][4] f32
    const int*   edges = (const int*)d_in[1];     // [320000] int
    const float* w     = (const float*)d_in[2];   // [4][320000][16] f32
    float* out = (float*)d_out;                   // [8][10000][16] f32
    float* xt  = (float*)d_ws;                    // (10001*32) floats = 1.28 MB

    int tr_total  = BATCH * N_NODES + 8;                  // 80008
    int tr_blocks = (tr_total + 255) / 256;               // 313
    lcg_transpose<<<tr_blocks, 256, 0, stream>>>(x, xt);

    lcg_main<<<P_COUNT, 1024, 0, stream>>>(xt, edges, w, out);
}